// Round 1
// baseline (413.753 us; speedup 1.0000x reference)
//
#include <hip/hip_runtime.h>

typedef __attribute__((ext_vector_type(8))) short short8;
typedef __attribute__((ext_vector_type(4))) float floatx4;
typedef __attribute__((ext_vector_type(4))) int intx4;

static __device__ __forceinline__ unsigned short f2bf(float x) {
    unsigned int u = __float_as_uint(x);
    u += 0x7fffu + ((u >> 16) & 1u);
    return (unsigned short)(u >> 16);
}

// 16-lane butterfly add via DPP (VALU pipe, not DS). Steps: quad xor1, quad xor2,
// row_half_mirror (== xor4 once quads uniform), row_mirror (== xor8 once halves uniform).
template <int CTRL>
static __device__ __forceinline__ float dpp_add(float x) {
    int v = __builtin_amdgcn_update_dpp(0, __float_as_int(x), CTRL, 0xf, 0xf, true);
    return x + __int_as_float(v);
}

// ---------------- K1: histogram of iid ----------------
__global__ void k_hist(const int* __restrict__ iid, int* __restrict__ counts, int N) {
    int n = blockIdx.x * blockDim.x + threadIdx.x;
    if (n < N) atomicAdd(&counts[iid[n]], 1);
}

// ---------------- K2: fp32->bf16 convert + count-weighted stats (one feat pass) ------
__global__ __launch_bounds__(256) void k_cvtstats(const float* __restrict__ feat,
                                                  const int* __restrict__ counts,
                                                  unsigned short* __restrict__ featb,
                                                  float* __restrict__ dsum, float* __restrict__ dsumsq,
                                                  int V) {
    int tid = threadIdx.x;
    int r2 = tid >> 7, d = tid & 127;
    float s = 0.f, qa = 0.f;
    for (int vp = blockIdx.x; vp * 2 < V; vp += gridDim.x) {
        int v = vp * 2 + r2;
        if (v >= V) continue;
        float f = feat[(size_t)v * 128 + d];
        featb[(size_t)v * 128 + d] = f2bf(f);
        float c = (float)counts[v];
        if (c != 0.f) { s += c * f; qa += c * f * f; }
    }
    __shared__ float red[256];
    red[tid] = s; __syncthreads();
    if (tid < 128) atomicAdd(&dsum[d], red[tid] + red[tid + 128]);
    __syncthreads();
    red[tid] = qa; __syncthreads();
    if (tid < 128) atomicAdd(&dsumsq[d], red[tid] + red[tid + 128]);
}

// ---------------- K3: BN affine constants ----------------
__global__ __launch_bounds__(128) void k_affine(const float* __restrict__ sum,
                                                const float* __restrict__ sumsq,
                                                const float* __restrict__ gamma,
                                                const float* __restrict__ beta,
                                                float* __restrict__ scale, float* __restrict__ shift,
                                                float invN) {
    int d = threadIdx.x;
    float mean = sum[d] * invN;
    float var  = sumsq[d] * invN - mean * mean;
    float sc   = gamma[d] * rsqrtf(var + 1e-5f);
    scale[d] = sc;
    shift[d] = beta[d] - mean * sc;
}

// ---------------- K4: fold scale into weights; fused bias ----------------
__global__ __launch_bounds__(128) void k_prep(const float* __restrict__ Wu, const float* __restrict__ Wv,
                                              const float* __restrict__ bv,
                                              const float* __restrict__ scale, const float* __restrict__ shift,
                                              unsigned short* __restrict__ wut, float* __restrict__ wvs,
                                              float* __restrict__ cbias) {
    int h = blockIdx.x, d = threadIdx.x;
    float sc = scale[d], sh = shift[d];
    float wu = Wu[d * 128 + h], wv = Wv[d * 128 + h];
    wut[h * 128 + d] = f2bf(sc * wu);
    wvs[d * 128 + h] = sc * wv;
    __shared__ float red[128];
    red[d] = sh * (wu + wv);
    __syncthreads();
    for (int off = 64; off > 0; off >>= 1) {
        if (d < off) red[d] += red[d + off];
        __syncthreads();
    }
    if (d == 0) cbias[h] = bv[h] + red[0];
}

// ---------------- K5: feat_v per graph ----------------
__global__ __launch_bounds__(128) void k_fv(const float* __restrict__ feat, const int* __restrict__ iid,
                                            const int* __restrict__ last, const float* __restrict__ wvs,
                                            const float* __restrict__ cbias, float* __restrict__ fv,
                                            int B) {
    const int GPB = 8;
    int b0 = blockIdx.x * GPB;
    int h = threadIdx.x;
    __shared__ float sx[GPB][128];
    for (int g = 0; g < GPB; ++g) {
        int b = b0 + g;
        if (b < B) {
            int row = iid[last[b]];
            sx[g][h] = feat[(size_t)row * 128 + h];
        }
    }
    __syncthreads();
    float acc[GPB];
#pragma unroll
    for (int g = 0; g < GPB; ++g) acc[g] = 0.f;
    for (int d = 0; d < 128; ++d) {
        float w = wvs[d * 128 + h];
#pragma unroll
        for (int g = 0; g < GPB; ++g) acc[g] += sx[g][d] * w;
    }
    float c = cbias[h];
    for (int g = 0; g < GPB; ++g)
        if (b0 + g < B) fv[(size_t)(b0 + g) * 128 + h] = acc[g] + c;
}

// ---------------- K6: pipelined e-kernel + FUSED per-segment weighted sum ----------------
// phase 1 (per tile): u = bf16(feat[iid]) @ Wu' + fv[seg]; partial e per wave -> sEp
// phase 2 (same tile, after barrier): ex = exp(sum sEp); accumulate ex*x (x already in LDS!)
// into rstAcc[seg][d] and den[seg] via run-accumulation + fp32 atomics on boundaries.
__global__ __launch_bounds__(256, 4) void k_main(
        const unsigned short* __restrict__ featb, const int* __restrict__ iid,
        const int* __restrict__ seg, const unsigned short* __restrict__ wut,
        const float* __restrict__ fv, const float* __restrict__ we_g,
        float* __restrict__ rstAcc, float* __restrict__ den,
        int N, int B, int numTiles) {
    __shared__ unsigned short sA[2][64 * 128];
    __shared__ int   sSeg[2][64];
    __shared__ float sFv[2][4][128];
    __shared__ float sEp[4][64];

    int tid = threadIdx.x;
    int wv = tid >> 6, lane = tid & 63, q = lane >> 4, c = lane & 15;
    int p2 = lane & 15;
    int rowbase = wv * 16 + (lane >> 4);

    // one-time B fragments in registers (2 h-tiles per wave)
    short8 bfr[2][4];
    float we2[2];
#pragma unroll
    for (int t = 0; t < 2; ++t) {
        int h = (2 * wv + t) * 16 + c;
        we2[t] = we_g[h];
#pragma unroll
        for (int kc = 0; kc < 4; ++kc)
            bfr[t][kc] = *(const short8*)(wut + h * 128 + kc * 32 + q * 8);
    }

    if (blockIdx.x >= numTiles) return;

    int iidR[4]; int segR; float2 fvR;
    auto loadRegs = [&](int T) {
        int n0 = T << 6;
#pragma unroll
        for (int k = 0; k < 4; ++k)
            iidR[k] = iid[min(n0 + rowbase + 4 * k, N - 1)];
        segR = seg[min(n0 + (tid & 63), N - 1)];
        int s0 = __builtin_amdgcn_readfirstlane(segR);   // seg[n0], no extra load
        int fvrow = min(s0 + (tid >> 6), B - 1);
        fvR = *(const float2*)(fv + (size_t)fvrow * 128 + ((tid << 1) & 127));
    };
    auto stage = [&](int buf) {
        unsigned short* sAb = &sA[buf][0];
#pragma unroll
        for (int k = 0; k < 4; ++k) {
            int row = rowbase + 4 * k;
            int j = (p2 & 8) | ((p2 & 7) ^ (row & 7));
            const unsigned short* g = featb + (size_t)iidR[k] * 128 + j * 8;
            __builtin_amdgcn_global_load_lds(
                (const __attribute__((address_space(1))) void*)g,
                (__attribute__((address_space(3))) void*)(sAb + wv * 2048 + k * 512),
                16, 0, 0);
        }
        if (tid < 64) sSeg[buf][tid] = segR;
        *(float2*)&sFv[buf][tid >> 6][(tid << 1) & 127] = fvR;
    };

    int T = blockIdx.x;
    loadRegs(T);
    stage(0);
    int cur = 0;

    for (;;) {
        int Tn = T + gridDim.x;
        bool hn = (Tn < numTiles);
        if (hn) loadRegs(Tn);
        __syncthreads();            // [1] buf[cur] staged complete; prev wsum readers done
        if (hn) stage(cur ^ 1);

        // ---- phase 1: MFMA + partial e for tile T from buf[cur] ----
        floatx4 acc[4][2];
#pragma unroll
        for (int mt = 0; mt < 4; ++mt)
#pragma unroll
            for (int t = 0; t < 2; ++t) acc[mt][t] = (floatx4)(0.f);
#pragma unroll
        for (int kc = 0; kc < 4; ++kc) {
            int jj = 4 * kc + q;
            int pofs = ((jj & 8) | ((jj & 7) ^ (c & 7))) * 8;
            short8 a0 = *(const short8*)&sA[cur][( 0 + c) * 128 + pofs];
            short8 a1 = *(const short8*)&sA[cur][(16 + c) * 128 + pofs];
            short8 a2 = *(const short8*)&sA[cur][(32 + c) * 128 + pofs];
            short8 a3 = *(const short8*)&sA[cur][(48 + c) * 128 + pofs];
#pragma unroll
            for (int t = 0; t < 2; ++t) {
                acc[0][t] = __builtin_amdgcn_mfma_f32_16x16x32_bf16(a0, bfr[t][kc], acc[0][t], 0, 0, 0);
                acc[1][t] = __builtin_amdgcn_mfma_f32_16x16x32_bf16(a1, bfr[t][kc], acc[1][t], 0, 0, 0);
                acc[2][t] = __builtin_amdgcn_mfma_f32_16x16x32_bf16(a2, bfr[t][kc], acc[2][t], 0, 0, 0);
                acc[3][t] = __builtin_amdgcn_mfma_f32_16x16x32_bf16(a3, bfr[t][kc], acc[3][t], 0, 0, 0);
            }
        }
        {
            int s0 = sSeg[cur][0];
            int h0 = wv * 32 + c;
#pragma unroll
            for (int mt = 0; mt < 4; ++mt)
#pragma unroll
                for (int r = 0; r < 4; ++r) {
                    int nl = mt * 16 + q * 4 + r;
                    int sg = sSeg[cur][nl];
                    int off = sg - s0;
                    float f0, f1;
                    if (off < 4) {
                        f0 = sFv[cur][off][h0];
                        f1 = sFv[cur][off][h0 + 16];
                    } else {
                        f0 = fv[((size_t)sg << 7) + h0];
                        f1 = fv[((size_t)sg << 7) + h0 + 16];
                    }
                    float u0 = acc[mt][0][r] + f0;
                    float u1 = acc[mt][1][r] + f1;
                    float p = we2[0] * __builtin_amdgcn_rcpf(1.f + __expf(-u0))
                            + we2[1] * __builtin_amdgcn_rcpf(1.f + __expf(-u1));
                    // 16-lane butterfly on VALU (DPP) instead of ds_swizzle
                    p = dpp_add<0xb1>(p);
                    p = dpp_add<0x4e>(p);
                    p = dpp_add<0x141>(p);
                    p = dpp_add<0x140>(p);
                    if (c == 0) sEp[wv][nl] = p;
                }
        }
        __syncthreads();            // [2] sEp complete; sA[cur] still valid

        // ---- phase 2: fused weighted sum for tile T ----
        {
            int n0 = T << 6;
            int nb = wv * 16;
            // ex for this wave's 16 nodes (uniform/broadcast LDS reads)
            float exr[16];
#pragma unroll
            for (int jg = 0; jg < 4; ++jg) {
                floatx4 e0 = *(const floatx4*)&sEp[0][nb + jg * 4];
                floatx4 e1 = *(const floatx4*)&sEp[1][nb + jg * 4];
                floatx4 e2 = *(const floatx4*)&sEp[2][nb + jg * 4];
                floatx4 e3 = *(const floatx4*)&sEp[3][nb + jg * 4];
#pragma unroll
                for (int r = 0; r < 4; ++r) {
                    float s = e0[r] + e1[r] + e2[r] + e3[r];
                    exr[jg * 4 + r] = (n0 + nb + jg * 4 + r < N) ? __expf(s) : 0.f;
                }
            }
            int sgr[16];
#pragma unroll
            for (int jg = 0; jg < 4; ++jg)
                *(intx4*)&sgr[jg * 4] = *(const intx4*)&sSeg[cur][nb + jg * 4];

            int d0 = lane * 2;          // this lane's d-pair
            int jj = lane >> 2;         // global 8-ushort chunk index of d0
            int wsub = (lane & 3) * 4;  // byte offset within chunk
            const char* base = (const char*)&sA[cur][0];
            float a0 = 0.f, a1 = 0.f, dl = 0.f;
            int curseg = sgr[0];
#pragma unroll
            for (int j = 0; j < 16; ++j) {
                int row = nb + j;
                int sg = sgr[j];
                if (sg != curseg) {     // wave-uniform branch (sorted segments)
                    atomicAdd(&rstAcc[(size_t)curseg * 128 + d0], a0);
                    atomicAdd(&rstAcc[(size_t)curseg * 128 + d0 + 1], a1);
                    if (lane == 0) atomicAdd(&den[curseg], dl);
                    a0 = a1 = dl = 0.f; curseg = sg;
                }
                int ch = (jj & 8) | ((jj & 7) ^ (row & 7));   // undo stage swizzle
                unsigned u = *(const unsigned*)(base + row * 256 + ch * 16 + wsub);
                float e = exr[j];
                a0 += e * __uint_as_float(u << 16);
                a1 += e * __uint_as_float(u & 0xffff0000u);
                dl += e;
            }
            atomicAdd(&rstAcc[(size_t)curseg * 128 + d0], a0);
            atomicAdd(&rstAcc[(size_t)curseg * 128 + d0 + 1], a1);
            if (lane == 0) atomicAdd(&den[curseg], dl);
        }

        if (!hn) break;
        T = Tn; cur ^= 1;
    }
}

// ---------------- K9: out = (scale*acc/den) @ W_out + [den>0]*(shift @ W_out) ----------------
__global__ __launch_bounds__(256) void k_out(const float* __restrict__ rstAcc,
                                             const float* __restrict__ den,
                                             const float* __restrict__ scale,
                                             const float* __restrict__ shift,
                                             const float* __restrict__ Wout,
                                             float* __restrict__ out, int B) {
    __shared__ float sT[128][36];
    __shared__ float sInv[32];
    int b0 = blockIdx.x * 32;
    int t = threadIdx.x;
    for (int i = 0; i < 16; ++i) {
        int idx = i * 256 + t;
        int r = idx >> 7, d = idx & 127;
        int b = min(b0 + r, B - 1);
        sT[d][r] = scale[d] * rstAcc[((size_t)b << 7) + d];
    }
    if (t < 32) {
        int b = min(b0 + t, B - 1);
        float dn = den[b];
        sInv[t] = (dn > 0.f) ? 1.f / dn : 0.f;
    }
    __syncthreads();
    float acc[32];
#pragma unroll
    for (int r = 0; r < 32; ++r) acc[r] = 0.f;
    float sb = 0.f;
    for (int dd = 0; dd < 128; ++dd) {
        float w = Wout[dd * 256 + t];
        sb += shift[dd] * w;
        const float4* row = (const float4*)&sT[dd][0];
#pragma unroll
        for (int r4 = 0; r4 < 8; ++r4) {
            float4 v = row[r4];
            acc[r4 * 4 + 0] += w * v.x;
            acc[r4 * 4 + 1] += w * v.y;
            acc[r4 * 4 + 2] += w * v.z;
            acc[r4 * 4 + 3] += w * v.w;
        }
    }
    for (int r = 0; r < 32; ++r)
        if (b0 + r < B) {
            float inv = sInv[r];
            out[(size_t)(b0 + r) * 256 + t] = acc[r] * inv + (inv != 0.f ? sb : 0.f);
        }
}

extern "C" void kernel_launch(void* const* d_in, const int* in_sizes, int n_in,
                              void* d_out, int out_size, void* d_ws, size_t ws_size,
                              hipStream_t stream) {
    const float* feat  = (const float*)d_in[0];
    const int*   iid   = (const int*)d_in[1];
    const int*   seg   = (const int*)d_in[2];
    const int*   last  = (const int*)d_in[3];
    const float* gamma = (const float*)d_in[4];
    const float* beta  = (const float*)d_in[5];
    const float* Wu    = (const float*)d_in[6];
    const float* Wv    = (const float*)d_in[7];
    const float* bv    = (const float*)d_in[8];
    const float* we    = (const float*)d_in[9];
    const float* Wout  = (const float*)d_in[10];
    float* out = (float*)d_out;

    int V = in_sizes[0] / 128;
    int N = in_sizes[1];
    int B = in_sizes[3];

    char* w = (char*)d_ws;
    size_t off = 0;
    auto alloc = [&](size_t bytes) -> void* {
        void* p = w + off;
        off += (bytes + 255) & ~(size_t)255;
        return p;
    };
    // zero-init region
    int*   counts = (int*)alloc((size_t)V * 4);
    float* dsum   = (float*)alloc(512);
    float* dsumsq = (float*)alloc(512);
    float* rstAcc = (float*)alloc((size_t)B * 128 * 4);
    float* den    = (float*)alloc((size_t)B * 4);
    size_t zero_bytes = off;
    // rest
    float* scale  = (float*)alloc(512);
    float* shift  = (float*)alloc(512);
    float* cbias  = (float*)alloc(512);
    unsigned short* wut = (unsigned short*)alloc(128 * 128 * 2);
    float* wvs    = (float*)alloc(128 * 128 * 4);
    float* fv     = (float*)alloc((size_t)B * 128 * 4);
    unsigned short* featb = (unsigned short*)alloc((size_t)V * 128 * 2);
    (void)ws_size; (void)n_in; (void)out_size;

    hipMemsetAsync(d_ws, 0, zero_bytes, stream);

    k_hist<<<(N + 255) / 256, 256, 0, stream>>>(iid, counts, N);
    k_cvtstats<<<1024, 256, 0, stream>>>(feat, counts, featb, dsum, dsumsq, V);
    k_affine<<<1, 128, 0, stream>>>(dsum, dsumsq, gamma, beta, scale, shift, 1.0f / (float)N);
    k_prep<<<128, 128, 0, stream>>>(Wu, Wv, bv, scale, shift, wut, wvs, cbias);
    k_fv<<<(B + 7) / 8, 128, 0, stream>>>(feat, iid, last, wvs, cbias, fv, B);

    int numTiles = (N + 63) / 64;
    k_main<<<1024, 256, 0, stream>>>(featb, iid, seg, wut, fv, we, rstAcc, den, N, B, numTiles);

    k_out<<<(B + 31) / 32, 256, 0, stream>>>(rstAcc, den, scale, shift, Wout, out, B);
}